// Round 1
// baseline (423.581 us; speedup 1.0000x reference)
//
#include <hip/hip_runtime.h>

// RUM cell, algebraically reduced:
//   R @ h = h + (cos-1)(a u + b v) + sin (a v - b u),  a = u.h, b = v.h
//   hidden_new = assoc_mem @ (R @ h)   -- batched matvec, reads 256MB once
// Shapes fixed: B=256, IN=512, H=512, 3H=1536.

#define EPSF 1e-12f

// ---------------- block-wide sum (256 threads = 4 waves) ----------------
__device__ __forceinline__ float block_reduce_sum(float v, float* sbuf) {
#pragma unroll
    for (int off = 32; off >= 1; off >>= 1)
        v += __shfl_xor(v, off, 64);
    const int t = threadIdx.x;
    __syncthreads();                    // protect sbuf reuse across calls
    if ((t & 63) == 0) sbuf[t >> 6] = v;
    __syncthreads();
    return sbuf[0] + sbuf[1] + sbuf[2] + sbuf[3];
}

// ---------------- K1: proj = [inp|hid] @ [W_ih|W_hh]^T + b_ih + b_hh ----
// Tiles: BM=32 batch rows, BN=64 out cols, BK=32. 256 thr, micro 2x4.
#define BM 32
#define BN 64
#define BK 32
#define XS_STRIDE (BM + 2)   // 34, keeps float2 LDS reads 8B-aligned

__global__ __launch_bounds__(256) void gemm_proj(
    const float* __restrict__ inp, const float* __restrict__ hid,
    const float* __restrict__ W_ih, const float* __restrict__ W_hh,
    const float* __restrict__ b_ih, const float* __restrict__ b_hh,
    float* __restrict__ proj)
{
    __shared__ float Xs[BK * XS_STRIDE];   // [k][m]
    __shared__ float Ws[BK * BN];          // [k][n]
    const int t  = threadIdx.x;
    const int tx = t & 15;                 // col group: cols 4*tx..+3
    const int ty = t >> 4;                 // row group: rows 2*ty..+1
    const int col0 = blockIdx.x * BN;
    const int row0 = blockIdx.y * BM;

    const int lr = t >> 3;                 // 0..31 load row
    const int lk = (t & 7) * 4;            // 0,4,..,28 load k

    float acc[2][4] = {};

#pragma unroll
    for (int phase = 0; phase < 2; ++phase) {
        const float* Xg = phase ? hid : inp;
        const float* Wg = phase ? W_hh : W_ih;
        for (int k0 = 0; k0 < 512; k0 += BK) {
            float4 xv  = *(const float4*)(Xg + (size_t)(row0 + lr) * 512 + k0 + lk);
            float4 wv0 = *(const float4*)(Wg + (size_t)(col0 + lr) * 512 + k0 + lk);
            float4 wv1 = *(const float4*)(Wg + (size_t)(col0 + lr + 32) * 512 + k0 + lk);
            __syncthreads();   // previous chunk's compute done
            Xs[(lk + 0) * XS_STRIDE + lr] = xv.x;
            Xs[(lk + 1) * XS_STRIDE + lr] = xv.y;
            Xs[(lk + 2) * XS_STRIDE + lr] = xv.z;
            Xs[(lk + 3) * XS_STRIDE + lr] = xv.w;
            Ws[(lk + 0) * BN + lr] = wv0.x;
            Ws[(lk + 1) * BN + lr] = wv0.y;
            Ws[(lk + 2) * BN + lr] = wv0.z;
            Ws[(lk + 3) * BN + lr] = wv0.w;
            Ws[(lk + 0) * BN + lr + 32] = wv1.x;
            Ws[(lk + 1) * BN + lr + 32] = wv1.y;
            Ws[(lk + 2) * BN + lr + 32] = wv1.z;
            Ws[(lk + 3) * BN + lr + 32] = wv1.w;
            __syncthreads();
#pragma unroll
            for (int kk = 0; kk < BK; ++kk) {
                float2 xv2 = *(const float2*)&Xs[kk * XS_STRIDE + 2 * ty];
                float4 wv4 = *(const float4*)&Ws[kk * BN + 4 * tx];
                acc[0][0] += xv2.x * wv4.x;
                acc[0][1] += xv2.x * wv4.y;
                acc[0][2] += xv2.x * wv4.z;
                acc[0][3] += xv2.x * wv4.w;
                acc[1][0] += xv2.y * wv4.x;
                acc[1][1] += xv2.y * wv4.y;
                acc[1][2] += xv2.y * wv4.z;
                acc[1][3] += xv2.y * wv4.w;
            }
        }
    }

    const float4 bi = *(const float4*)(b_ih + col0 + 4 * tx);
    const float4 bh = *(const float4*)(b_hh + col0 + 4 * tx);
    const float4 bias = { bi.x + bh.x, bi.y + bh.y, bi.z + bh.z, bi.w + bh.w };
#pragma unroll
    for (int i = 0; i < 2; ++i) {
        const int r = row0 + 2 * ty + i;
        float4 o = { acc[i][0] + bias.x, acc[i][1] + bias.y,
                     acc[i][2] + bias.z, acc[i][3] + bias.w };
        *(float4*)(proj + (size_t)r * 1536 + col0 + 4 * tx) = o;
    }
}

// ---------------- K2: per-batch-row rotation -> Rh = R @ hidden ---------
__global__ __launch_bounds__(256) void rotate_kernel(
    const float* __restrict__ proj, const float* __restrict__ hid,
    float* __restrict__ Rh)
{
    __shared__ float sbuf[4];
    const int b = blockIdx.x;
    const int t = threadIdx.x;
    const int j = 2 * t;
    const float* prow = proj + (size_t)b * 1536;
    const float2 x2 = *(const float2*)(prow + 1024 + j);   // x_emb
    const float2 r2 = *(const float2*)(prow + 512 + j);    // r
    const float2 h2 = *(const float2*)(hid + (size_t)b * 512 + j);

    float sx2 = block_reduce_sum(x2.x * x2.x + x2.y * x2.y, sbuf);
    float sr2 = block_reduce_sum(r2.x * r2.x + r2.y * r2.y, sbuf);
    float sxr = block_reduce_sum(x2.x * r2.x + x2.y * r2.y, sbuf);
    float sxh = block_reduce_sum(x2.x * h2.x + x2.y * h2.y, sbuf);

    const float nx = fmaxf(sqrtf(sx2), EPSF);
    const float nr = fmaxf(sqrtf(sr2), EPSF);
    const float costh = sxr / (nx * nr);
    const float sinth = sqrtf(fmaxf(1.0f - costh * costh, 0.0f));
    const float dot_ur = sxr / nx;     // u . r
    const float a = sxh / nx;          // u . h

    const float ux = x2.x / nx, uy = x2.y / nx;
    const float wx = r2.x - dot_ur * ux, wy = r2.y - dot_ur * uy;

    float sw2 = block_reduce_sum(wx * wx + wy * wy, sbuf);
    float swh = block_reduce_sum(wx * h2.x + wy * h2.y, sbuf);
    const float nw = fmaxf(sqrtf(sw2), EPSF);
    const float bb = swh / nw;         // v . h

    const float cm1 = costh - 1.0f;
    const float vx = wx / nw, vy = wy / nw;
    float2 o;
    o.x = h2.x + cm1 * (a * ux + bb * vx) + sinth * (a * vx - bb * ux);
    o.y = h2.y + cm1 * (a * uy + bb * vy) + sinth * (a * vy - bb * uy);
    *(float2*)(Rh + (size_t)b * 512 + j) = o;
}

// ---------------- K3: hidden_new = assoc_mem @ Rh (batched matvec) ------
// grid (8 row-groups, 256 batches); block 256 = 4 waves; wave-per-row.
__global__ __launch_bounds__(256) void matvec_kernel(
    const float* __restrict__ A, const float* __restrict__ Rh,
    float* __restrict__ hn)
{
    __shared__ float Rhs[512];
    const int b = blockIdx.y;
    const int g = blockIdx.x;            // 0..7
    const int t = threadIdx.x;
    *(float2*)(Rhs + 2 * t) = *(const float2*)(Rh + (size_t)b * 512 + 2 * t);
    __syncthreads();
    const int wave = t >> 6, lane = t & 63;
    const float4* Rhs4 = (const float4*)Rhs;
    const float4 x0 = Rhs4[lane];
    const float4 x1 = Rhs4[64 + lane];
    float res = 0.0f;
#pragma unroll 4
    for (int rr = 0; rr < 16; ++rr) {
        const int i = g * 64 + wave * 16 + rr;
        const float4* Arow = (const float4*)(A + ((size_t)b * 512 + i) * 512);
        const float4 a0 = Arow[lane];
        const float4 a1 = Arow[64 + lane];
        float acc = a0.x * x0.x + a0.y * x0.y + a0.z * x0.z + a0.w * x0.w
                  + a1.x * x1.x + a1.y * x1.y + a1.z * x1.z + a1.w * x1.w;
#pragma unroll
        for (int off = 32; off >= 1; off >>= 1)
            acc += __shfl_xor(acc, off, 64);
        if (lane == rr) res = acc;       // lane rr keeps row rr's sum
    }
    if (lane < 16)
        hn[(size_t)b * 512 + g * 64 + wave * 16 + lane] = res;
}

// ---------------- K4: gate + relu + l2norm ------------------------------
__global__ __launch_bounds__(256) void epilogue_kernel(
    const float* __restrict__ proj, const float* __restrict__ hid,
    const float* __restrict__ hn, float* __restrict__ out)
{
    __shared__ float sbuf[4];
    const int b = blockIdx.x;
    const int t = threadIdx.x;
    const int j = 2 * t;
    const float* prow = proj + (size_t)b * 1536;
    const float2 ug = *(const float2*)(prow + j);          // u_gate
    const float2 xe = *(const float2*)(prow + 1024 + j);   // x_emb
    const float2 h2 = *(const float2*)(hid + (size_t)b * 512 + j);
    const float2 hv = *(const float2*)(hn + (size_t)b * 512 + j);

    const float cx = fmaxf(hv.x + xe.x, 0.0f);
    const float cy = fmaxf(hv.y + xe.y, 0.0f);
    const float tx_ = ug.x * h2.x + (1.0f - ug.x) * cx;
    const float ty_ = ug.y * h2.y + (1.0f - ug.y) * cy;

    const float s = block_reduce_sum(tx_ * tx_ + ty_ * ty_, sbuf);
    const float inv = 1.0f / fmaxf(sqrtf(s), EPSF);   // ETA = 1
    float2 o = { tx_ * inv, ty_ * inv };
    *(float2*)(out + (size_t)b * 512 + j) = o;
}

extern "C" void kernel_launch(void* const* d_in, const int* in_sizes, int n_in,
                              void* d_out, int out_size, void* d_ws, size_t ws_size,
                              hipStream_t stream)
{
    const float* inp  = (const float*)d_in[0];   // [256,512]
    const float* hid  = (const float*)d_in[1];   // [256,512]
    const float* A    = (const float*)d_in[2];   // [256,512,512]
    const float* W_ih = (const float*)d_in[3];   // [1536,512]
    const float* b_ih = (const float*)d_in[4];   // [1536]
    const float* W_hh = (const float*)d_in[5];   // [1536,512]
    const float* b_hh = (const float*)d_in[6];   // [1536]
    float* out = (float*)d_out;                  // [256,512]

    // workspace: proj 1.5MB | Rh 0.5MB | hn 0.5MB  (total 2.5MB)
    float* proj = (float*)d_ws;
    float* Rh   = proj + 256 * 1536;
    float* hn   = Rh + 256 * 512;

    gemm_proj<<<dim3(24, 8), 256, 0, stream>>>(inp, hid, W_ih, W_hh, b_ih, b_hh, proj);
    rotate_kernel<<<dim3(256), 256, 0, stream>>>(proj, hid, Rh);
    matvec_kernel<<<dim3(8, 256), 256, 0, stream>>>(A, Rh, hn);
    epilogue_kernel<<<dim3(256), 256, 0, stream>>>(proj, hid, hn, out);
}

// Round 3
// 385.752 us; speedup vs baseline: 1.0981x; 1.0981x over previous
//
#include <hip/hip_runtime.h>

// RUM cell, algebraically reduced:
//   R @ h = h + (cos-1)(a u + b v) + sin (a v - b u),  a = u.h, b = v.h
//   hidden_new = assoc_mem @ (R @ h)   -- batched matvec, reads 256MB once
// Shapes fixed: B=256, IN=512, H=512, 3H=1536.
// Round 3: fix nontemporal-load type (needs native vector type, not float4).

#define EPSF 1e-12f

typedef float vfloat4 __attribute__((ext_vector_type(4)));

// ---------------- K1: proj = [inp|hid] @ [W_ih|W_hh]^T + b_ih + b_hh ----
// BM=32, BN=64, BK=32, 256 thr, 2x4 micro, register prefetch of next chunk.
__global__ __launch_bounds__(256) void gemm_proj(
    const float* __restrict__ inp, const float* __restrict__ hid,
    const float* __restrict__ W_ih, const float* __restrict__ W_hh,
    const float* __restrict__ b_ih, const float* __restrict__ b_hh,
    float* __restrict__ proj)
{
    __shared__ float Xs[32 * 34];   // [k][m], +2 pad
    __shared__ float Ws[32 * 64];   // [k][n]
    const int t  = threadIdx.x;
    const int tx = t & 15;                 // cols 4*tx..+3
    const int ty = t >> 4;                 // rows 2*ty..+1
    const int col0 = blockIdx.x * 64;
    const int row0 = blockIdx.y * 32;
    const int lr = t >> 3;                 // 0..31 load row
    const int lk = (t & 7) * 4;            // 0,4,..,28 load k

    float acc[2][4] = {};

    // prefetch chunk 0 (phase 0 = inputs/W_ih)
    float4 xv  = *(const float4*)(inp  + (size_t)(row0 + lr) * 512 + lk);
    float4 wv0 = *(const float4*)(W_ih + (size_t)(col0 + lr) * 512 + lk);
    float4 wv1 = *(const float4*)(W_ih + (size_t)(col0 + lr + 32) * 512 + lk);

    for (int cc = 0; cc < 32; ++cc) {
        __syncthreads();   // previous chunk's compute done (LDS WAR)
        Xs[(lk + 0) * 34 + lr] = xv.x;
        Xs[(lk + 1) * 34 + lr] = xv.y;
        Xs[(lk + 2) * 34 + lr] = xv.z;
        Xs[(lk + 3) * 34 + lr] = xv.w;
        Ws[(lk + 0) * 64 + lr] = wv0.x;
        Ws[(lk + 1) * 64 + lr] = wv0.y;
        Ws[(lk + 2) * 64 + lr] = wv0.z;
        Ws[(lk + 3) * 64 + lr] = wv0.w;
        Ws[(lk + 0) * 64 + lr + 32] = wv1.x;
        Ws[(lk + 1) * 64 + lr + 32] = wv1.y;
        Ws[(lk + 2) * 64 + lr + 32] = wv1.z;
        Ws[(lk + 3) * 64 + lr + 32] = wv1.w;

        // prefetch next chunk before compute (hides global latency)
        const int nc = (cc < 31) ? cc + 1 : 31;
        const float* Xg = (nc & 16) ? hid  : inp;
        const float* Wg = (nc & 16) ? W_hh : W_ih;
        const int k0 = (nc & 15) * 32;
        xv  = *(const float4*)(Xg + (size_t)(row0 + lr) * 512 + k0 + lk);
        wv0 = *(const float4*)(Wg + (size_t)(col0 + lr) * 512 + k0 + lk);
        wv1 = *(const float4*)(Wg + (size_t)(col0 + lr + 32) * 512 + k0 + lk);

        __syncthreads();   // LDS stores visible
#pragma unroll
        for (int kk = 0; kk < 32; ++kk) {
            float2 xv2 = *(const float2*)&Xs[kk * 34 + 2 * ty];
            float4 wv4 = *(const float4*)&Ws[kk * 64 + 4 * tx];
            acc[0][0] += xv2.x * wv4.x;
            acc[0][1] += xv2.x * wv4.y;
            acc[0][2] += xv2.x * wv4.z;
            acc[0][3] += xv2.x * wv4.w;
            acc[1][0] += xv2.y * wv4.x;
            acc[1][1] += xv2.y * wv4.y;
            acc[1][2] += xv2.y * wv4.z;
            acc[1][3] += xv2.y * wv4.w;
        }
    }

    const float4 bi = *(const float4*)(b_ih + col0 + 4 * tx);
    const float4 bh = *(const float4*)(b_hh + col0 + 4 * tx);
    const float4 bias = { bi.x + bh.x, bi.y + bh.y, bi.z + bh.z, bi.w + bh.w };
#pragma unroll
    for (int i = 0; i < 2; ++i) {
        const int r = row0 + 2 * ty + i;
        float4 o = { acc[i][0] + bias.x, acc[i][1] + bias.y,
                     acc[i][2] + bias.z, acc[i][3] + bias.w };
        *(float4*)(proj + (size_t)r * 1536 + col0 + 4 * tx) = o;
    }
}

// ---------------- K2: fused rotate + batched matvec + epilogue ----------
// One block (1024 thr = 16 waves) per batch row b. Streams A[b] (1 MB).

__device__ __forceinline__ float4 block_reduce4_1024(float4 v, float4* red, int t) {
    __syncthreads();                 // protect red reuse across passes
#pragma unroll
    for (int off = 32; off >= 1; off >>= 1) {
        v.x += __shfl_xor(v.x, off, 64);
        v.y += __shfl_xor(v.y, off, 64);
        v.z += __shfl_xor(v.z, off, 64);
        v.w += __shfl_xor(v.w, off, 64);
    }
    if ((t & 63) == 0) red[t >> 6] = v;
    __syncthreads();
    float4 s = {0.f, 0.f, 0.f, 0.f};
#pragma unroll
    for (int i = 0; i < 16; ++i) {
        float4 r = red[i];
        s.x += r.x; s.y += r.y; s.z += r.z; s.w += r.w;
    }
    return s;
}

__global__ __launch_bounds__(1024) void rum_fused(
    const float* __restrict__ proj, const float* __restrict__ hid,
    const float* __restrict__ A, float* __restrict__ out)
{
    __shared__ float4 Rh4[128];      // R @ hidden, 512 floats
    __shared__ float  hn[512];       // assoc_mem @ Rh
    __shared__ float4 red[16];
    float* Rh = (float*)Rh4;

    const int b = blockIdx.x;
    const int t = threadIdx.x;       // 0..1023
    const float* prow = proj + (size_t)b * 1536;

    // ---- stage 1: rotation vectors, Rh = R @ h (threads 0..511 own elem t)
    float xe = 0.f, rr = 0.f, hh = 0.f;
    if (t < 512) {
        xe = prow[1024 + t];
        rr = prow[512 + t];
        hh = hid[(size_t)b * 512 + t];
    }
    float4 p1 = { xe * xe, rr * rr, xe * rr, xe * hh };
    p1 = block_reduce4_1024(p1, red, t);
    const float nx = fmaxf(sqrtf(p1.x), EPSF);
    const float nr = fmaxf(sqrtf(p1.y), EPSF);
    const float costh = p1.z / (nx * nr);
    const float sinth = sqrtf(fmaxf(1.0f - costh * costh, 0.0f));
    const float dot_ur = p1.z / nx;      // u . r
    const float a = p1.w / nx;           // u . h
    const float u = xe / nx;
    const float w = rr - dot_ur * u;

    float4 p2 = { w * w, w * hh, 0.f, 0.f };
    p2 = block_reduce4_1024(p2, red, t);
    const float nw = fmaxf(sqrtf(p2.x), EPSF);
    const float bb = p2.y / nw;          // v . h
    const float v = w / nw;
    const float cm1 = costh - 1.0f;
    if (t < 512)
        Rh[t] = hh + cm1 * (a * u + bb * v) + sinth * (a * v - bb * u);
    __syncthreads();

    // ---- stage 2: hn = A[b] @ Rh. Wave wv rows [32wv,32wv+32), 4 rows/pass,
    //      16 lanes per row (c), 4-step xor reduce within 16-lane groups.
    const int lane = t & 63;
    const int wv = t >> 6;               // 0..15
    const int g = lane >> 4;             // row-in-quad 0..3
    const int c = lane & 15;             // column lane

    float4 xr[8];
#pragma unroll
    for (int k = 0; k < 8; ++k) xr[k] = Rh4[c + 16 * k];

    const vfloat4* Ab = (const vfloat4*)(A + (size_t)b * 512 * 512);
#pragma unroll 2
    for (int q = 0; q < 8; ++q) {
        const int i = 32 * wv + 4 * q + g;
        const vfloat4* Ar = Ab + (size_t)i * 128;
        float a0 = 0.f, a1 = 0.f, a2 = 0.f, a3 = 0.f;
#pragma unroll
        for (int k = 0; k < 8; k += 4) {
            vfloat4 v0 = __builtin_nontemporal_load(Ar + c + 16 * (k + 0));
            vfloat4 v1 = __builtin_nontemporal_load(Ar + c + 16 * (k + 1));
            vfloat4 v2 = __builtin_nontemporal_load(Ar + c + 16 * (k + 2));
            vfloat4 v3 = __builtin_nontemporal_load(Ar + c + 16 * (k + 3));
            a0 += v0.x * xr[k + 0].x + v0.y * xr[k + 0].y + v0.z * xr[k + 0].z + v0.w * xr[k + 0].w;
            a1 += v1.x * xr[k + 1].x + v1.y * xr[k + 1].y + v1.z * xr[k + 1].z + v1.w * xr[k + 1].w;
            a2 += v2.x * xr[k + 2].x + v2.y * xr[k + 2].y + v2.z * xr[k + 2].z + v2.w * xr[k + 2].w;
            a3 += v3.x * xr[k + 3].x + v3.y * xr[k + 3].y + v3.z * xr[k + 3].z + v3.w * xr[k + 3].w;
        }
        float accq = (a0 + a1) + (a2 + a3);
#pragma unroll
        for (int off = 8; off >= 1; off >>= 1)
            accq += __shfl_xor(accq, off, 16);
        if (c == 0) hn[i] = accq;
    }
    __syncthreads();

    // ---- stage 3: gate + relu + l2norm
    float tv = 0.f, ug = 0.f;
    if (t < 512) {
        ug = prow[t];
        const float cx = fmaxf(hn[t] + xe, 0.0f);
        tv = ug * hh + (1.0f - ug) * cx;
    }
    float4 p3 = { tv * tv, 0.f, 0.f, 0.f };
    p3 = block_reduce4_1024(p3, red, t);
    const float inv = 1.0f / fmaxf(sqrtf(p3.x), EPSF);   // ETA = 1
    if (t < 512)
        out[(size_t)b * 512 + t] = tv * inv;
}

extern "C" void kernel_launch(void* const* d_in, const int* in_sizes, int n_in,
                              void* d_out, int out_size, void* d_ws, size_t ws_size,
                              hipStream_t stream)
{
    const float* inp  = (const float*)d_in[0];   // [256,512]
    const float* hid  = (const float*)d_in[1];   // [256,512]
    const float* A    = (const float*)d_in[2];   // [256,512,512]
    const float* W_ih = (const float*)d_in[3];   // [1536,512]
    const float* b_ih = (const float*)d_in[4];   // [1536]
    const float* W_hh = (const float*)d_in[5];   // [1536,512]
    const float* b_hh = (const float*)d_in[6];   // [1536]
    float* out = (float*)d_out;                  // [256,512]

    float* proj = (float*)d_ws;                  // 1.5 MB workspace

    gemm_proj<<<dim3(24, 8), 256, 0, stream>>>(inp, hid, W_ih, W_hh, b_ih, b_hh, proj);
    rum_fused<<<dim3(256), 1024, 0, stream>>>(proj, hid, A, out);
}